// Round 7
// baseline (420.711 us; speedup 1.0000x reference)
//
#include <hip/hip_runtime.h>

#define N_NODES 20000
#define E_EDGES 160000
#define NFEAT   512
#define NHID    512
#define NCLASS  64
#define NLAYERS 4

#define SCAN_CHUNK 1024
#define NBLK ((N_NODES + SCAN_CHUNK - 1) / SCAN_CHUNK)   // 20
#define CNT_BLOCKS ((E_EDGES + 255) / 256)               // 625

using bf16x8 = __attribute__((ext_vector_type(8))) short;          // MFMA A/B frag
using f32x4  = __attribute__((ext_vector_type(4))) float;          // MFMA C/D frag
using u16x8  = __attribute__((ext_vector_type(8))) unsigned short; // 16B bf16 vector

__device__ __forceinline__ unsigned short f2bf(float f) {
    union { float f; unsigned int u; } v; v.f = f;
    unsigned int u = v.u + 0x7FFFu + ((v.u >> 16) & 1u);   // RNE
    return (unsigned short)(u >> 16);
}
__device__ __forceinline__ float bf2f(unsigned short h) {
    union { unsigned int u; float f; } v; v.u = ((unsigned int)h) << 16;
    return v.f;
}
__device__ __forceinline__ void gl2lds16(const void* gptr, void* lptr) {
    __builtin_amdgcn_global_load_lds(
        (const __attribute__((address_space(1))) unsigned int*)gptr,
        (__attribute__((address_space(3))) unsigned int*)lptr,
        16, 0, 0);
}

// ================= fused prep: edge counting + chunk bins + weight transposes ==
__global__ __launch_bounds__(256) void prep_all(const int* __restrict__ dst,
                                                int* __restrict__ counts,
                                                int* __restrict__ bsums,
                                                const float* __restrict__ W_enc,
                                                const float* __restrict__ W_convs,
                                                const float* __restrict__ W_dec,
                                                unsigned short* __restrict__ WencT,
                                                unsigned short* __restrict__ WcvT,
                                                unsigned short* __restrict__ WdecT) {
    __shared__ int bins[NBLK];
    __shared__ float tile[32][33];
    const int b = blockIdx.x, t = threadIdx.x;

    if (b < CNT_BLOCKS) {
        if (t < NBLK) bins[t] = 0;
        __syncthreads();
        const int e = b * 256 + t;
        if (e < E_EDGES) {
            const int d = dst[e];
            atomicAdd(&counts[d], 1);
            atomicAdd(&bins[d >> 10], 1);         // SCAN_CHUNK = 1024
        }
        __syncthreads();
        if (t < NBLK && bins[t]) atomicAdd(&bsums[t], bins[t]);
        return;
    }

    // ---- transpose role ----
    const int bid = b - CNT_BLOCKS;
    const int id  = bid >> 8;            // matrix 0..5
    const int rem = bid & 255;
    const int n0  = (rem & 15) * 32;
    const int k0  = (rem >> 4) * 32;
    const float* W; unsigned short* WT; int N;
    const int K = 512;
    if (id == 0)            { W = W_enc; WT = WencT; N = NHID; }
    else if (id <= NLAYERS) { W = W_convs + (size_t)(id - 1) * NHID * NHID;
                              WT = WcvT  + (size_t)(id - 1) * NHID * NHID; N = NHID; }
    else                    { W = W_dec; WT = WdecT; N = NCLASS; }
    if (n0 >= N) return;
    const int tx = t & 31, ty = t >> 5;
#pragma unroll
    for (int i = 0; i < 32; i += 8)
        tile[ty + i][tx] = W[(size_t)(k0 + ty + i) * N + n0 + tx];
    __syncthreads();
#pragma unroll
    for (int i = 0; i < 32; i += 8)
        WT[(size_t)(n0 + ty + i) * K + k0 + tx] = f2bf(tile[tx][ty + i]);
}

// ================= scan =================
__global__ __launch_bounds__(64) void scan_bsums(const int* __restrict__ bsums,
                                                 int* __restrict__ boffs) {
    const int t = threadIdx.x;
    const int orig = (t < NBLK) ? bsums[t] : 0;
    int v = orig;
    for (int off = 1; off < 64; off <<= 1) {
        int u = __shfl_up(v, off, 64);
        if (t >= off) v += u;
    }
    if (t < NBLK) boffs[t] = v - orig;   // exclusive
}

// row_ptr + cursor + dinv in one pass
__global__ __launch_bounds__(256) void write_rowptr(const int* __restrict__ counts,
                                                    const int* __restrict__ boffs,
                                                    int* __restrict__ row_ptr,
                                                    int* __restrict__ cursor,
                                                    float* __restrict__ dinv) {
    __shared__ int part[256];
    const int b = blockIdx.x, t = threadIdx.x;
    const int base = b * SCAN_CHUNK + t * 4;
    int c[4], s = 0;
    for (int i = 0; i < 4; ++i) {
        int idx = base + i;
        c[i] = (idx < N_NODES) ? counts[idx] : 0;
        s += c[i];
    }
    part[t] = s;
    __syncthreads();
    for (int off = 1; off < 256; off <<= 1) {
        int v = (t >= off) ? part[t - off] : 0;
        __syncthreads();
        part[t] += v;
        __syncthreads();
    }
    int run = boffs[b] + ((t == 0) ? 0 : part[t - 1]);
    for (int i = 0; i < 4; ++i) {
        int idx = base + i;
        if (idx < N_NODES) {
            row_ptr[idx] = run;
            cursor[idx]  = run;
            dinv[idx]    = rsqrtf((float)c[i] + 1.0f);
            run += c[i];
        }
    }
    if (b == 0 && t == 0) row_ptr[N_NODES] = E_EDGES;
}

// fill packed (col, wgt) pairs; pad 8 entries past E with {node 0, weight 0}
__global__ __launch_bounds__(256) void csr_fill(const int* __restrict__ src,
                                                const int* __restrict__ dst,
                                                const float* __restrict__ dinv,
                                                int* __restrict__ cursor,
                                                int2* __restrict__ ew) {
    int e = blockIdx.x * 256 + threadIdx.x;
    if (e < E_EDGES) {
        int s = src[e], d = dst[e];
        int pos = atomicAdd(&cursor[d], 1);
        ew[pos] = make_int2(s, __float_as_int(dinv[s] * dinv[d]));
    }
    if (e < 8) ew[E_EDGES + e] = make_int2(0, 0);
}

// ================= bf16 MFMA GEMM, BM=32 x BN=full-width =================
// C[M,N] = A[M,K] @ B[K,N]; BT = B^T bf16 [N][K]. One block per 32-row slab
// covering ALL N columns -> A fetched exactly once (no n-block duplication);
// B^T (<=512KB) is XCD-L2-resident. LDS double-buffered: tile kt+1 prefetched
// via global_load_lds while MFMAing tile kt. M must be divisible by 32.
template <int BN, bool RELU, bool HASBIAS, bool OUTBF16, bool A32>
__global__ __launch_bounds__(256, 2) void gemm_mfma(const void* __restrict__ Aptr,
                                                    const unsigned short* __restrict__ BT,
                                                    const float* __restrict__ bias,
                                                    void* __restrict__ Cout,
                                                    int M, int N, int K) {
    constexpr int BM = 32, BK = 32;
    constexpr int C  = BN / 64;              // col-frags per wave (8 or 1)
    constexpr int R  = 2;                    // row-frags per wave
    constexpr int NB = (BN * BK) / 2048;     // B staging rounds (8 or 1)
    __shared__ unsigned short lA[2][BM * BK];   // 2 x 2 KB
    __shared__ unsigned short lB[2][BN * BK];   // 2 x 32 KB (BN=512)

    const int t    = threadIdx.x;
    const int lane = t & 63;
    const int wv   = t >> 6;
    const int lm   = lane & 15;
    const int quad = lane >> 4;
    const int m0   = blockIdx.x * BM;

    auto stage = [&](int kt, int buf) {
        if constexpr (!A32) {
            if (t < 128) {                      // 32x32 bf16 = 2 KB = 128 lanes x 16B
                const int row = t >> 2, kof = (t & 3) << 3;
                gl2lds16((const unsigned short*)Aptr + (size_t)(m0 + row) * K + kt + kof,
                         &lA[buf][t * 8]);
            }
        } else {                                // fp32 A: load->convert->ds_write
            const int row = t >> 3, kof = (t & 7) << 2;
            const float* p = (const float*)Aptr + (size_t)(m0 + row) * K + kt + kof;
            float4 f = *(const float4*)p;
            ushort4 pk;
            pk.x = f2bf(f.x); pk.y = f2bf(f.y); pk.z = f2bf(f.z); pk.w = f2bf(f.w);
            *(ushort4*)&lA[buf][t * 4] = pk;
        }
#pragma unroll
        for (int i = 0; i < NB; ++i) {
            const int idx = i * 256 + t;
            const int row = idx >> 2, kof = (idx & 3) << 3;
            gl2lds16(BT + (size_t)row * K + kt + kof, &lB[buf][idx * 8]);
        }
    };

    f32x4 acc[R][C] = {};
    stage(0, 0);
    __syncthreads();

    const int NIT = K / BK;
    for (int it = 0; it < NIT; ++it) {
        const int cur = it & 1;
        if (it + 1 < NIT) stage((it + 1) * BK, cur ^ 1);   // async prefetch

        bf16x8 af[R], bfr[C];
#pragma unroll
        for (int r = 0; r < R; ++r)
            af[r] = *(const bf16x8*)&lA[cur][(r * 16 + lm) * BK + quad * 8];
#pragma unroll
        for (int c = 0; c < C; ++c)
            bfr[c] = *(const bf16x8*)&lB[cur][((wv * C + c) * 16 + lm) * BK + quad * 8];
#pragma unroll
        for (int r = 0; r < R; ++r)
#pragma unroll
            for (int c = 0; c < C; ++c)
                acc[r][c] = __builtin_amdgcn_mfma_f32_16x16x32_bf16(af[r], bfr[c],
                                                                    acc[r][c], 0, 0, 0);
        __syncthreads();   // drains prefetch vmcnt + protects cur buffer
    }

    // epilogue: C/D layout col=lane&15, row=quad*4+reg
#pragma unroll
    for (int r = 0; r < R; ++r) {
#pragma unroll
        for (int c = 0; c < C; ++c) {
            const int colg = (wv * C + c) * 16 + lm;
            const float bb = HASBIAS ? bias[colg] : 0.0f;
            const int rowb = m0 + r * 16 + quad * 4;
#pragma unroll
            for (int i = 0; i < 4; ++i) {
                float v = acc[r][c][i] + bb;
                if (RELU) v = fmaxf(v, 0.0f);
                if (OUTBF16)
                    ((unsigned short*)Cout)[(size_t)(rowb + i) * N + colg] = f2bf(v);
                else
                    ((float*)Cout)[(size_t)(rowb + i) * N + colg] = v;
            }
        }
    }
}

// ================= CSR-pull aggregation =================
__global__ __launch_bounds__(256) void gcn_aggregate(const unsigned short* __restrict__ hW,
                                                     const int* __restrict__ row_ptr,
                                                     const int2* __restrict__ ew,
                                                     const float* __restrict__ dinv,
                                                     const float* __restrict__ bias,
                                                     unsigned short* __restrict__ out) {
    const int wv   = threadIdx.x >> 6;
    const int lane = threadIdx.x & 63;
    int d = blockIdx.x * 4 + wv;
    d = __builtin_amdgcn_readfirstlane(d);
    if (d >= N_NODES) return;
    const int beg = __builtin_amdgcn_readfirstlane(row_ptr[d]);
    const int end = __builtin_amdgcn_readfirstlane(row_ptr[d + 1]);
    const size_t foff = (size_t)lane * 8;

    const float di = dinv[d];
    const float sl = di * di;
    u16x8 sv = *(const u16x8*)(hW + (size_t)d * NHID + foff);
    float acc[8];
#pragma unroll
    for (int i = 0; i < 8; ++i) acc[i] = bf2f(sv[i]) * sl;

    for (int j = beg; j < end; j += 8) {
        int   sK[8];
        float wK[8];
        u16x8 v[8];
#pragma unroll
        for (int k = 0; k < 8; ++k) {
            const int jj = j + k;            // may overrun into pad (safe)
            const int2 e = ew[jj];
            const bool valid = jj < end;     // wave-uniform
            sK[k] = valid ? e.x : 0;
            wK[k] = valid ? __int_as_float(e.y) : 0.0f;
        }
#pragma unroll
        for (int k = 0; k < 8; ++k)
            v[k] = *(const u16x8*)(hW + (size_t)sK[k] * NHID + foff);
#pragma unroll
        for (int k = 0; k < 8; ++k)
#pragma unroll
            for (int i = 0; i < 8; ++i)
                acc[i] += bf2f(v[k][i]) * wK[k];
    }

    const float4 b0v = *(const float4*)(bias + foff);
    const float4 b1v = *(const float4*)(bias + foff + 4);
    u16x8 r;
    r[0] = f2bf(fmaxf(acc[0] + b0v.x, 0.0f));
    r[1] = f2bf(fmaxf(acc[1] + b0v.y, 0.0f));
    r[2] = f2bf(fmaxf(acc[2] + b0v.z, 0.0f));
    r[3] = f2bf(fmaxf(acc[3] + b0v.w, 0.0f));
    r[4] = f2bf(fmaxf(acc[4] + b1v.x, 0.0f));
    r[5] = f2bf(fmaxf(acc[5] + b1v.y, 0.0f));
    r[6] = f2bf(fmaxf(acc[6] + b1v.z, 0.0f));
    r[7] = f2bf(fmaxf(acc[7] + b1v.w, 0.0f));
    *(u16x8*)(out + (size_t)d * NHID + foff) = r;
}

// ================= launch =================
extern "C" void kernel_launch(void* const* d_in, const int* in_sizes, int n_in,
                              void* d_out, int out_size, void* d_ws, size_t ws_size,
                              hipStream_t stream) {
    const float* x       = (const float*)d_in[0];
    const int*   ei      = (const int*)d_in[1];
    const float* W_enc   = (const float*)d_in[2];
    const float* b_enc   = (const float*)d_in[3];
    const float* W_convs = (const float*)d_in[4];
    const float* b_convs = (const float*)d_in[5];
    const float* W_dec   = (const float*)d_in[6];
    const float* b_dec   = (const float*)d_in[7];
    float* out = (float*)d_out;

    const int* src = ei;
    const int* dst = ei + E_EDGES;

    char* ws = (char*)d_ws;
    auto alloc = [&](size_t bytes) {
        char* p = ws;
        ws += (bytes + 255) / 256 * 256;
        return p;
    };
    float* dinv     = (float*)alloc(N_NODES * 4);
    int*   counts   = (int*)  alloc((N_NODES + NBLK) * 4);   // bsums adjacent
    int*   bsums    = counts + N_NODES;
    int*   row_ptr  = (int*)  alloc((N_NODES + 1) * 4);
    int*   cursor   = (int*)  alloc(N_NODES * 4);
    int*   boffs    = (int*)  alloc(NBLK * 4);
    int2*  ew       = (int2*) alloc((E_EDGES + 8) * 8);
    unsigned short* WencT = (unsigned short*)alloc((size_t)NFEAT * NHID * 2);
    unsigned short* WcvT  = (unsigned short*)alloc((size_t)NLAYERS * NHID * NHID * 2);
    unsigned short* WdecT = (unsigned short*)alloc((size_t)NHID * NCLASS * 2);
    unsigned short* B1    = (unsigned short*)alloc((size_t)N_NODES * NHID * 2);
    unsigned short* B2    = (unsigned short*)alloc((size_t)N_NODES * NHID * 2);

    // ---- CSR build + weight conversion (fused) ----
    hipMemsetAsync(counts, 0, (N_NODES + NBLK) * sizeof(int), stream);
    prep_all<<<CNT_BLOCKS + 6 * 256, 256, 0, stream>>>(
        dst, counts, bsums, W_enc, W_convs, W_dec, WencT, WcvT, WdecT);
    scan_bsums<<<1, 64, 0, stream>>>(bsums, boffs);
    write_rowptr<<<NBLK, 256, 0, stream>>>(counts, boffs, row_ptr, cursor, dinv);
    csr_fill<<<(E_EDGES + 255) / 256, 256, 0, stream>>>(src, dst, dinv, cursor, ew);

    const int MB = N_NODES / 32;            // 625, exact

    // ---- encoder (reads fp32 x, converts in staging) ----
    gemm_mfma<512, true, true, true, true><<<MB, 256, 0, stream>>>(
        x, WencT, b_enc, B1, N_NODES, NHID, NFEAT);

    // ---- conv layers ----
    for (int L = 0; L < NLAYERS; ++L) {
        gemm_mfma<512, false, false, true, false><<<MB, 256, 0, stream>>>(
            B1, WcvT + (size_t)L * NHID * NHID, nullptr, B2, N_NODES, NHID, NHID);
        gcn_aggregate<<<(N_NODES + 3) / 4, 256, 0, stream>>>(
            B2, row_ptr, ew, dinv, b_convs + (size_t)L * NHID, B1);
    }

    // ---- decoder ----
    gemm_mfma<64, false, true, false, false><<<MB, 256, 0, stream>>>(
        B1, WdecT, b_dec, out, N_NODES, NCLASS, NHID);
}

// Round 8
// 352.774 us; speedup vs baseline: 1.1926x; 1.1926x over previous
//
#include <hip/hip_runtime.h>

#define N_NODES 20000
#define E_EDGES 160000
#define NFEAT   512
#define NHID    512
#define NCLASS  64
#define NLAYERS 4

#define SCAN_CHUNK 1024
#define NBLK ((N_NODES + SCAN_CHUNK - 1) / SCAN_CHUNK)   // 20
#define CNT_BLOCKS ((E_EDGES + 255) / 256)               // 625

using bf16x8 = __attribute__((ext_vector_type(8))) short;          // MFMA A/B frag
using f32x4  = __attribute__((ext_vector_type(4))) float;          // MFMA C/D frag
using u16x8  = __attribute__((ext_vector_type(8))) unsigned short; // 16B bf16 vector

__device__ __forceinline__ unsigned short f2bf(float f) {
    union { float f; unsigned int u; } v; v.f = f;
    unsigned int u = v.u + 0x7FFFu + ((v.u >> 16) & 1u);   // RNE
    return (unsigned short)(u >> 16);
}
__device__ __forceinline__ float bf2f(unsigned short h) {
    union { unsigned int u; float f; } v; v.u = ((unsigned int)h) << 16;
    return v.f;
}
__device__ __forceinline__ void gl2lds16(const void* gptr, void* lptr) {
    __builtin_amdgcn_global_load_lds(
        (const __attribute__((address_space(1))) unsigned int*)gptr,
        (__attribute__((address_space(3))) unsigned int*)lptr,
        16, 0, 0);
}

// ================= fused prep: edge counting + chunk bins + weight transposes ==
__global__ __launch_bounds__(256) void prep_all(const int* __restrict__ dst,
                                                int* __restrict__ counts,
                                                int* __restrict__ bsums,
                                                const float* __restrict__ W_enc,
                                                const float* __restrict__ W_convs,
                                                const float* __restrict__ W_dec,
                                                unsigned short* __restrict__ WencT,
                                                unsigned short* __restrict__ WcvT,
                                                unsigned short* __restrict__ WdecT) {
    __shared__ int bins[NBLK];
    __shared__ float tile[32][33];
    const int b = blockIdx.x, t = threadIdx.x;

    if (b < CNT_BLOCKS) {
        if (t < NBLK) bins[t] = 0;
        __syncthreads();
        const int e = b * 256 + t;
        if (e < E_EDGES) {
            const int d = dst[e];
            atomicAdd(&counts[d], 1);
            atomicAdd(&bins[d >> 10], 1);         // SCAN_CHUNK = 1024
        }
        __syncthreads();
        if (t < NBLK && bins[t]) atomicAdd(&bsums[t], bins[t]);
        return;
    }

    // ---- transpose role ----
    const int bid = b - CNT_BLOCKS;
    const int id  = bid >> 8;            // matrix 0..5
    const int rem = bid & 255;
    const int n0  = (rem & 15) * 32;
    const int k0  = (rem >> 4) * 32;
    const float* W; unsigned short* WT; int N;
    const int K = 512;
    if (id == 0)            { W = W_enc; WT = WencT; N = NHID; }
    else if (id <= NLAYERS) { W = W_convs + (size_t)(id - 1) * NHID * NHID;
                              WT = WcvT  + (size_t)(id - 1) * NHID * NHID; N = NHID; }
    else                    { W = W_dec; WT = WdecT; N = NCLASS; }
    if (n0 >= N) return;
    const int tx = t & 31, ty = t >> 5;
#pragma unroll
    for (int i = 0; i < 32; i += 8)
        tile[ty + i][tx] = W[(size_t)(k0 + ty + i) * N + n0 + tx];
    __syncthreads();
#pragma unroll
    for (int i = 0; i < 32; i += 8)
        WT[(size_t)(n0 + ty + i) * K + k0 + tx] = f2bf(tile[tx][ty + i]);
}

// ================= scan =================
__global__ __launch_bounds__(64) void scan_bsums(const int* __restrict__ bsums,
                                                 int* __restrict__ boffs) {
    const int t = threadIdx.x;
    const int orig = (t < NBLK) ? bsums[t] : 0;
    int v = orig;
    for (int off = 1; off < 64; off <<= 1) {
        int u = __shfl_up(v, off, 64);
        if (t >= off) v += u;
    }
    if (t < NBLK) boffs[t] = v - orig;   // exclusive
}

// row_ptr + cursor + dinv in one pass
__global__ __launch_bounds__(256) void write_rowptr(const int* __restrict__ counts,
                                                    const int* __restrict__ boffs,
                                                    int* __restrict__ row_ptr,
                                                    int* __restrict__ cursor,
                                                    float* __restrict__ dinv) {
    __shared__ int part[256];
    const int b = blockIdx.x, t = threadIdx.x;
    const int base = b * SCAN_CHUNK + t * 4;
    int c[4], s = 0;
    for (int i = 0; i < 4; ++i) {
        int idx = base + i;
        c[i] = (idx < N_NODES) ? counts[idx] : 0;
        s += c[i];
    }
    part[t] = s;
    __syncthreads();
    for (int off = 1; off < 256; off <<= 1) {
        int v = (t >= off) ? part[t - off] : 0;
        __syncthreads();
        part[t] += v;
        __syncthreads();
    }
    int run = boffs[b] + ((t == 0) ? 0 : part[t - 1]);
    for (int i = 0; i < 4; ++i) {
        int idx = base + i;
        if (idx < N_NODES) {
            row_ptr[idx] = run;
            cursor[idx]  = run;
            dinv[idx]    = rsqrtf((float)c[i] + 1.0f);
            run += c[i];
        }
    }
    if (b == 0 && t == 0) row_ptr[N_NODES] = E_EDGES;
}

// fill packed (col, wgt) pairs; pad 8 entries past E with {node 0, weight 0}
__global__ __launch_bounds__(256) void csr_fill(const int* __restrict__ src,
                                                const int* __restrict__ dst,
                                                const float* __restrict__ dinv,
                                                int* __restrict__ cursor,
                                                int2* __restrict__ ew) {
    int e = blockIdx.x * 256 + threadIdx.x;
    if (e < E_EDGES) {
        int s = src[e], d = dst[e];
        int pos = atomicAdd(&cursor[d], 1);
        ew[pos] = make_int2(s, __float_as_int(dinv[s] * dinv[d]));
    }
    if (e < 8) ew[E_EDGES + e] = make_int2(0, 0);
}

// ================= bf16 MFMA GEMM (R6 structure + XCD-aware swizzle) =========
// C[M,N] = A[M,K] @ B[K,N]; BT = B^T bf16 [N][K]. BM=128, BK=32.
// 1-D grid, block id swizzled so the NBN n-blocks sharing one m-slab land on
// the SAME XCD (dispatch is round-robin over 8 XCDs) in consecutive rounds:
// A-slab fetched once into that XCD's L2, re-read as L2 hits (was 4x HBM).
template <int BN, bool RELU, bool HASBIAS, bool OUTBF16, bool A32>
__global__ __launch_bounds__(256) void gemm_mfma(const void* __restrict__ Aptr,
                                                 const unsigned short* __restrict__ BT,
                                                 const float* __restrict__ bias,
                                                 void* __restrict__ Cout,
                                                 int M, int N, int K) {
    constexpr int BM = 128, BK = 32;
    constexpr int R = (BN == 128) ? 4 : 2;
    constexpr int C = 4;
    __shared__ unsigned short lA[BM * BK];
    __shared__ unsigned short lB[BN * BK];

    const int t    = threadIdx.x;
    const int lane = t & 63;
    const int wv   = t >> 6;
    const int wr   = (BN == 128) ? (wv >> 1) : wv;
    const int wc   = (BN == 128) ? (wv & 1) : 0;
    const int lm   = lane & 15;
    const int quad = lane >> 4;

    // ---- XCD-aware swizzle: groups of 8*NBN ids = 8 m-slabs x NBN n-blocks,
    //      same-m on same (id % 8) = same XCD.
    const int MBLK = (M + BM - 1) / BM;
    const int NBN  = N / BN;
    int mblk, nblk;
    {
        const int i    = blockIdx.x;
        const int full = (MBLK / 8) * 8 * NBN;   // ids in complete groups
        if (i < full) {
            const int g = i / (8 * NBN);
            const int l = i % (8 * NBN);
            mblk = g * 8 + (l & 7);
            nblk = l >> 3;
        } else {
            const int t2  = i - full;
            const int rem = MBLK - (MBLK / 8) * 8;
            mblk = (MBLK / 8) * 8 + t2 % rem;
            nblk = t2 / rem;
        }
    }
    const int m0 = mblk * BM;
    const int n0 = nblk * BN;

    f32x4 acc[R][C] = {};

    for (int kt = 0; kt < K; kt += BK) {
        // ---- stage A tile ----
#pragma unroll
        for (int i = 0; i < (BM * BK) / (256 * 8); ++i) {
            int idx = i * 256 + t;
            int row = idx >> 2;
            int kof = (idx & 3) << 3;
            int gr = m0 + row; if (gr >= M) gr = M - 1;
            if constexpr (!A32) {
                gl2lds16((const unsigned short*)Aptr + (size_t)gr * K + kt + kof,
                         &lA[idx * 8]);
            } else {
                const float* p = (const float*)Aptr + (size_t)gr * K + kt + kof;
                float4 f0 = *(const float4*)p;
                float4 f1 = *(const float4*)(p + 4);
                u16x8 pk;
                pk[0] = f2bf(f0.x); pk[1] = f2bf(f0.y);
                pk[2] = f2bf(f0.z); pk[3] = f2bf(f0.w);
                pk[4] = f2bf(f1.x); pk[5] = f2bf(f1.y);
                pk[6] = f2bf(f1.z); pk[7] = f2bf(f1.w);
                *(u16x8*)&lA[idx * 8] = pk;
            }
        }
        // ---- stage B^T tile ----
#pragma unroll
        for (int i = 0; i < (BN * BK) / (256 * 8); ++i) {
            int idx = i * 256 + t;
            int row = idx >> 2;
            int kof = (idx & 3) << 3;
            gl2lds16(BT + (size_t)(n0 + row) * K + kt + kof, &lB[idx * 8]);
        }
        __syncthreads();

        bf16x8 af[R], bfr[C];
#pragma unroll
        for (int r = 0; r < R; ++r)
            af[r] = *(const bf16x8*)&lA[(wr * R * 16 + r * 16 + lm) * BK + quad * 8];
#pragma unroll
        for (int c = 0; c < C; ++c)
            bfr[c] = *(const bf16x8*)&lB[(wc * C * 16 + c * 16 + lm) * BK + quad * 8];
#pragma unroll
        for (int r = 0; r < R; ++r)
#pragma unroll
            for (int c = 0; c < C; ++c)
                acc[r][c] = __builtin_amdgcn_mfma_f32_16x16x32_bf16(af[r], bfr[c],
                                                                    acc[r][c], 0, 0, 0);
        __syncthreads();
    }

#pragma unroll
    for (int r = 0; r < R; ++r) {
#pragma unroll
        for (int c = 0; c < C; ++c) {
            const int colg = n0 + wc * C * 16 + c * 16 + lm;
            const float bb = HASBIAS ? bias[colg] : 0.0f;
            const int rowb = m0 + wr * R * 16 + r * 16 + quad * 4;
#pragma unroll
            for (int i = 0; i < 4; ++i) {
                const int rr = rowb + i;
                if (rr < M) {
                    float v = acc[r][c][i] + bb;
                    if (RELU) v = fmaxf(v, 0.0f);
                    if (OUTBF16)
                        ((unsigned short*)Cout)[(size_t)rr * N + colg] = f2bf(v);
                    else
                        ((float*)Cout)[(size_t)rr * N + colg] = v;
                }
            }
        }
    }
}

// ================= CSR-pull aggregation =================
__global__ __launch_bounds__(256) void gcn_aggregate(const unsigned short* __restrict__ hW,
                                                     const int* __restrict__ row_ptr,
                                                     const int2* __restrict__ ew,
                                                     const float* __restrict__ dinv,
                                                     const float* __restrict__ bias,
                                                     unsigned short* __restrict__ out) {
    const int wv   = threadIdx.x >> 6;
    const int lane = threadIdx.x & 63;
    int d = blockIdx.x * 4 + wv;
    d = __builtin_amdgcn_readfirstlane(d);
    if (d >= N_NODES) return;
    const int beg = __builtin_amdgcn_readfirstlane(row_ptr[d]);
    const int end = __builtin_amdgcn_readfirstlane(row_ptr[d + 1]);
    const size_t foff = (size_t)lane * 8;

    const float di = dinv[d];
    const float sl = di * di;
    u16x8 sv = *(const u16x8*)(hW + (size_t)d * NHID + foff);
    float acc[8];
#pragma unroll
    for (int i = 0; i < 8; ++i) acc[i] = bf2f(sv[i]) * sl;

    for (int j = beg; j < end; j += 8) {
        int   sK[8];
        float wK[8];
        u16x8 v[8];
#pragma unroll
        for (int k = 0; k < 8; ++k) {
            const int jj = j + k;            // may overrun into pad (safe)
            const int2 e = ew[jj];
            const bool valid = jj < end;     // wave-uniform
            sK[k] = valid ? e.x : 0;
            wK[k] = valid ? __int_as_float(e.y) : 0.0f;
        }
#pragma unroll
        for (int k = 0; k < 8; ++k)
            v[k] = *(const u16x8*)(hW + (size_t)sK[k] * NHID + foff);
#pragma unroll
        for (int k = 0; k < 8; ++k)
#pragma unroll
            for (int i = 0; i < 8; ++i)
                acc[i] += bf2f(v[k][i]) * wK[k];
    }

    const float4 b0v = *(const float4*)(bias + foff);
    const float4 b1v = *(const float4*)(bias + foff + 4);
    u16x8 r;
    r[0] = f2bf(fmaxf(acc[0] + b0v.x, 0.0f));
    r[1] = f2bf(fmaxf(acc[1] + b0v.y, 0.0f));
    r[2] = f2bf(fmaxf(acc[2] + b0v.z, 0.0f));
    r[3] = f2bf(fmaxf(acc[3] + b0v.w, 0.0f));
    r[4] = f2bf(fmaxf(acc[4] + b1v.x, 0.0f));
    r[5] = f2bf(fmaxf(acc[5] + b1v.y, 0.0f));
    r[6] = f2bf(fmaxf(acc[6] + b1v.z, 0.0f));
    r[7] = f2bf(fmaxf(acc[7] + b1v.w, 0.0f));
    *(u16x8*)(out + (size_t)d * NHID + foff) = r;
}

// ================= launch =================
extern "C" void kernel_launch(void* const* d_in, const int* in_sizes, int n_in,
                              void* d_out, int out_size, void* d_ws, size_t ws_size,
                              hipStream_t stream) {
    const float* x       = (const float*)d_in[0];
    const int*   ei      = (const int*)d_in[1];
    const float* W_enc   = (const float*)d_in[2];
    const float* b_enc   = (const float*)d_in[3];
    const float* W_convs = (const float*)d_in[4];
    const float* b_convs = (const float*)d_in[5];
    const float* W_dec   = (const float*)d_in[6];
    const float* b_dec   = (const float*)d_in[7];
    float* out = (float*)d_out;

    const int* src = ei;
    const int* dst = ei + E_EDGES;

    char* ws = (char*)d_ws;
    auto alloc = [&](size_t bytes) {
        char* p = ws;
        ws += (bytes + 255) / 256 * 256;
        return p;
    };
    float* dinv     = (float*)alloc(N_NODES * 4);
    int*   counts   = (int*)  alloc((N_NODES + NBLK) * 4);   // bsums adjacent
    int*   bsums    = counts + N_NODES;
    int*   row_ptr  = (int*)  alloc((N_NODES + 1) * 4);
    int*   cursor   = (int*)  alloc(N_NODES * 4);
    int*   boffs    = (int*)  alloc(NBLK * 4);
    int2*  ew       = (int2*) alloc((E_EDGES + 8) * 8);
    unsigned short* WencT = (unsigned short*)alloc((size_t)NFEAT * NHID * 2);
    unsigned short* WcvT  = (unsigned short*)alloc((size_t)NLAYERS * NHID * NHID * 2);
    unsigned short* WdecT = (unsigned short*)alloc((size_t)NHID * NCLASS * 2);
    unsigned short* B1    = (unsigned short*)alloc((size_t)N_NODES * NHID * 2);
    unsigned short* B2    = (unsigned short*)alloc((size_t)N_NODES * NHID * 2);

    // ---- CSR build + weight conversion (fused) ----
    hipMemsetAsync(counts, 0, (N_NODES + NBLK) * sizeof(int), stream);
    prep_all<<<CNT_BLOCKS + 6 * 256, 256, 0, stream>>>(
        dst, counts, bsums, W_enc, W_convs, W_dec, WencT, WcvT, WdecT);
    scan_bsums<<<1, 64, 0, stream>>>(bsums, boffs);
    write_rowptr<<<NBLK, 256, 0, stream>>>(counts, boffs, row_ptr, cursor, dinv);
    csr_fill<<<(E_EDGES + 255) / 256, 256, 0, stream>>>(src, dst, dinv, cursor, ew);

    const int MBLK = (N_NODES + 127) / 128;   // 157

    // ---- encoder (reads fp32 x, converts in staging) ----
    gemm_mfma<128, true, true, true, true><<<MBLK * (NHID / 128), 256, 0, stream>>>(
        x, WencT, b_enc, B1, N_NODES, NHID, NFEAT);

    // ---- conv layers ----
    for (int L = 0; L < NLAYERS; ++L) {
        gemm_mfma<128, false, false, true, false><<<MBLK * (NHID / 128), 256, 0, stream>>>(
            B1, WcvT + (size_t)L * NHID * NHID, nullptr, B2, N_NODES, NHID, NHID);
        gcn_aggregate<<<(N_NODES + 3) / 4, 256, 0, stream>>>(
            B2, row_ptr, ew, dinv, b_convs + (size_t)L * NHID, B1);
    }

    // ---- decoder ----
    gemm_mfma<64, false, true, false, false><<<MBLK * (NCLASS / 64), 256, 0, stream>>>(
        B1, WdecT, b_dec, out, N_NODES, NCLASS, NHID);
}

// Round 9
// 337.536 us; speedup vs baseline: 1.2464x; 1.0451x over previous
//
#include <hip/hip_runtime.h>

#define N_NODES 20000
#define E_EDGES 160000
#define NFEAT   512
#define NHID    512
#define NCLASS  64
#define NLAYERS 4

#define SCAN_CHUNK 1024
#define NBLK ((N_NODES + SCAN_CHUNK - 1) / SCAN_CHUNK)   // 20
#define CNT_BLOCKS ((E_EDGES + 255) / 256)               // 625

using bf16x8 = __attribute__((ext_vector_type(8))) short;          // MFMA A/B frag
using f32x4  = __attribute__((ext_vector_type(4))) float;          // MFMA C/D frag
using u16x8  = __attribute__((ext_vector_type(8))) unsigned short; // 16B bf16 vector

__device__ __forceinline__ unsigned short f2bf(float f) {
    union { float f; unsigned int u; } v; v.f = f;
    unsigned int u = v.u + 0x7FFFu + ((v.u >> 16) & 1u);   // RNE
    return (unsigned short)(u >> 16);
}
__device__ __forceinline__ float bf2f(unsigned short h) {
    union { unsigned int u; float f; } v; v.u = ((unsigned int)h) << 16;
    return v.f;
}
__device__ __forceinline__ void gl2lds16(const void* gptr, void* lptr) {
    __builtin_amdgcn_global_load_lds(
        (const __attribute__((address_space(1))) unsigned int*)gptr,
        (__attribute__((address_space(3))) unsigned int*)lptr,
        16, 0, 0);
}

// ================= fused prep: edge counting + chunk bins + weight transposes ==
__global__ __launch_bounds__(256) void prep_all(const int* __restrict__ dst,
                                                int* __restrict__ counts,
                                                int* __restrict__ bsums,
                                                const float* __restrict__ W_enc,
                                                const float* __restrict__ W_convs,
                                                const float* __restrict__ W_dec,
                                                unsigned short* __restrict__ WencT,
                                                unsigned short* __restrict__ WcvT,
                                                unsigned short* __restrict__ WdecT) {
    __shared__ int bins[NBLK];
    __shared__ float tile[32][33];
    const int b = blockIdx.x, t = threadIdx.x;

    if (b < CNT_BLOCKS) {
        if (t < NBLK) bins[t] = 0;
        __syncthreads();
        const int e = b * 256 + t;
        if (e < E_EDGES) {
            const int d = dst[e];
            atomicAdd(&counts[d], 1);
            atomicAdd(&bins[d >> 10], 1);         // SCAN_CHUNK = 1024
        }
        __syncthreads();
        if (t < NBLK && bins[t]) atomicAdd(&bsums[t], bins[t]);
        return;
    }

    // ---- transpose role ----
    const int bid = b - CNT_BLOCKS;
    const int id  = bid >> 8;            // matrix 0..5
    const int rem = bid & 255;
    const int n0  = (rem & 15) * 32;
    const int k0  = (rem >> 4) * 32;
    const float* W; unsigned short* WT; int N;
    const int K = 512;
    if (id == 0)            { W = W_enc; WT = WencT; N = NHID; }
    else if (id <= NLAYERS) { W = W_convs + (size_t)(id - 1) * NHID * NHID;
                              WT = WcvT  + (size_t)(id - 1) * NHID * NHID; N = NHID; }
    else                    { W = W_dec; WT = WdecT; N = NCLASS; }
    if (n0 >= N) return;
    const int tx = t & 31, ty = t >> 5;
#pragma unroll
    for (int i = 0; i < 32; i += 8)
        tile[ty + i][tx] = W[(size_t)(k0 + ty + i) * N + n0 + tx];
    __syncthreads();
#pragma unroll
    for (int i = 0; i < 32; i += 8)
        WT[(size_t)(n0 + ty + i) * K + k0 + tx] = f2bf(tile[tx][ty + i]);
}

// ================= scan =================
__global__ __launch_bounds__(64) void scan_bsums(const int* __restrict__ bsums,
                                                 int* __restrict__ boffs) {
    const int t = threadIdx.x;
    const int orig = (t < NBLK) ? bsums[t] : 0;
    int v = orig;
    for (int off = 1; off < 64; off <<= 1) {
        int u = __shfl_up(v, off, 64);
        if (t >= off) v += u;
    }
    if (t < NBLK) boffs[t] = v - orig;   // exclusive
}

// row_ptr + cursor + dinv in one pass
__global__ __launch_bounds__(256) void write_rowptr(const int* __restrict__ counts,
                                                    const int* __restrict__ boffs,
                                                    int* __restrict__ row_ptr,
                                                    int* __restrict__ cursor,
                                                    float* __restrict__ dinv) {
    __shared__ int part[256];
    const int b = blockIdx.x, t = threadIdx.x;
    const int base = b * SCAN_CHUNK + t * 4;
    int c[4], s = 0;
    for (int i = 0; i < 4; ++i) {
        int idx = base + i;
        c[i] = (idx < N_NODES) ? counts[idx] : 0;
        s += c[i];
    }
    part[t] = s;
    __syncthreads();
    for (int off = 1; off < 256; off <<= 1) {
        int v = (t >= off) ? part[t - off] : 0;
        __syncthreads();
        part[t] += v;
        __syncthreads();
    }
    int run = boffs[b] + ((t == 0) ? 0 : part[t - 1]);
    for (int i = 0; i < 4; ++i) {
        int idx = base + i;
        if (idx < N_NODES) {
            row_ptr[idx] = run;
            cursor[idx]  = run;
            dinv[idx]    = rsqrtf((float)c[i] + 1.0f);
            run += c[i];
        }
    }
    if (b == 0 && t == 0) row_ptr[N_NODES] = E_EDGES;
}

// fill packed (col, wgt) pairs; pad 8 entries past E with {node 0, weight 0}
__global__ __launch_bounds__(256) void csr_fill(const int* __restrict__ src,
                                                const int* __restrict__ dst,
                                                const float* __restrict__ dinv,
                                                int* __restrict__ cursor,
                                                int2* __restrict__ ew) {
    int e = blockIdx.x * 256 + threadIdx.x;
    if (e < E_EDGES) {
        int s = src[e], d = dst[e];
        int pos = atomicAdd(&cursor[d], 1);
        ew[pos] = make_int2(s, __float_as_int(dinv[s] * dinv[d]));
    }
    if (e < 8) ew[E_EDGES + e] = make_int2(0, 0);
}

// ================= bf16 MFMA GEMM =================
// C[M,N] = A[M,K] @ B[K,N]; BT = B^T bf16 [N][K]. BK=32, 256 threads = 4 waves
// arranged WR x WC; per-wave frag grid R x C. Small tile (64x128) -> grid
// ~1252 blocks = ~4.9 blocks/CU so inter-block overlap hides the staging
// latency the 2.45-blocks/CU 128x128 version exposed (R8 post-mortem).
// XCD swizzle: same-m n-blocks land on same XCD -> A-slab L2 reuse.
template <int BM, int BN, int WR, int WC, bool RELU, bool HASBIAS, bool OUTBF16, bool A32>
__global__ __launch_bounds__(256) void gemm_mfma(const void* __restrict__ Aptr,
                                                 const unsigned short* __restrict__ BT,
                                                 const float* __restrict__ bias,
                                                 void* __restrict__ Cout,
                                                 int M, int N, int K) {
    constexpr int BK = 32;
    constexpr int R  = BM / (16 * WR);
    constexpr int C  = BN / (16 * WC);
    constexpr int RA = (BM * BK) / (256 * 8);   // A staging rounds
    constexpr int RB = (BN * BK) / (256 * 8);   // B staging rounds
    __shared__ unsigned short lA[BM * BK];
    __shared__ unsigned short lB[BN * BK];

    const int t    = threadIdx.x;
    const int lane = t & 63;
    const int wv   = t >> 6;
    const int wr   = wv / WC;
    const int wc   = wv % WC;
    const int lm   = lane & 15;
    const int quad = lane >> 4;

    // ---- XCD-aware swizzle: groups of 8 m-slabs x NBN n-blocks; same-m on
    //      same (id % 8) = same XCD (round-robin dispatch).
    const int MBLK = (M + BM - 1) / BM;
    const int NBN  = N / BN;
    int mblk, nblk;
    {
        const int i    = blockIdx.x;
        const int full = (MBLK / 8) * 8 * NBN;
        if (i < full) {
            const int g = i / (8 * NBN);
            const int l = i % (8 * NBN);
            mblk = g * 8 + (l & 7);
            nblk = l >> 3;
        } else {
            const int t2  = i - full;
            const int rem = MBLK - (MBLK / 8) * 8;
            mblk = (MBLK / 8) * 8 + t2 % rem;
            nblk = t2 / rem;
        }
    }
    const int m0 = mblk * BM;
    const int n0 = nblk * BN;

    f32x4 acc[R][C] = {};

    for (int kt = 0; kt < K; kt += BK) {
        // ---- stage A tile ----
#pragma unroll
        for (int i = 0; i < RA; ++i) {
            int idx = i * 256 + t;
            int row = idx >> 2;
            int kof = (idx & 3) << 3;
            int gr = m0 + row; if (gr >= M) gr = M - 1;
            if constexpr (!A32) {
                gl2lds16((const unsigned short*)Aptr + (size_t)gr * K + kt + kof,
                         &lA[idx * 8]);
            } else {
                const float* p = (const float*)Aptr + (size_t)gr * K + kt + kof;
                float4 f0 = *(const float4*)p;
                float4 f1 = *(const float4*)(p + 4);
                u16x8 pk;
                pk[0] = f2bf(f0.x); pk[1] = f2bf(f0.y);
                pk[2] = f2bf(f0.z); pk[3] = f2bf(f0.w);
                pk[4] = f2bf(f1.x); pk[5] = f2bf(f1.y);
                pk[6] = f2bf(f1.z); pk[7] = f2bf(f1.w);
                *(u16x8*)&lA[idx * 8] = pk;
            }
        }
        // ---- stage B^T tile ----
#pragma unroll
        for (int i = 0; i < RB; ++i) {
            int idx = i * 256 + t;
            int row = idx >> 2;
            int kof = (idx & 3) << 3;
            gl2lds16(BT + (size_t)(n0 + row) * K + kt + kof, &lB[idx * 8]);
        }
        __syncthreads();

        bf16x8 af[R], bfr[C];
#pragma unroll
        for (int r = 0; r < R; ++r)
            af[r] = *(const bf16x8*)&lA[(wr * R * 16 + r * 16 + lm) * BK + quad * 8];
#pragma unroll
        for (int c = 0; c < C; ++c)
            bfr[c] = *(const bf16x8*)&lB[(wc * C * 16 + c * 16 + lm) * BK + quad * 8];
#pragma unroll
        for (int r = 0; r < R; ++r)
#pragma unroll
            for (int c = 0; c < C; ++c)
                acc[r][c] = __builtin_amdgcn_mfma_f32_16x16x32_bf16(af[r], bfr[c],
                                                                    acc[r][c], 0, 0, 0);
        __syncthreads();
    }

    // epilogue: C/D layout col=lane&15, row=quad*4+reg
#pragma unroll
    for (int r = 0; r < R; ++r) {
#pragma unroll
        for (int c = 0; c < C; ++c) {
            const int colg = n0 + wc * C * 16 + c * 16 + lm;
            const float bb = HASBIAS ? bias[colg] : 0.0f;
            const int rowb = m0 + wr * R * 16 + r * 16 + quad * 4;
#pragma unroll
            for (int i = 0; i < 4; ++i) {
                const int rr = rowb + i;
                if (rr < M) {
                    float v = acc[r][c][i] + bb;
                    if (RELU) v = fmaxf(v, 0.0f);
                    if (OUTBF16)
                        ((unsigned short*)Cout)[(size_t)rr * N + colg] = f2bf(v);
                    else
                        ((float*)Cout)[(size_t)rr * N + colg] = v;
                }
            }
        }
    }
}

// ================= CSR-pull aggregation =================
__global__ __launch_bounds__(256) void gcn_aggregate(const unsigned short* __restrict__ hW,
                                                     const int* __restrict__ row_ptr,
                                                     const int2* __restrict__ ew,
                                                     const float* __restrict__ dinv,
                                                     const float* __restrict__ bias,
                                                     unsigned short* __restrict__ out) {
    const int wv   = threadIdx.x >> 6;
    const int lane = threadIdx.x & 63;
    int d = blockIdx.x * 4 + wv;
    d = __builtin_amdgcn_readfirstlane(d);
    if (d >= N_NODES) return;
    const int beg = __builtin_amdgcn_readfirstlane(row_ptr[d]);
    const int end = __builtin_amdgcn_readfirstlane(row_ptr[d + 1]);
    const size_t foff = (size_t)lane * 8;

    const float di = dinv[d];
    const float sl = di * di;
    u16x8 sv = *(const u16x8*)(hW + (size_t)d * NHID + foff);
    float acc[8];
#pragma unroll
    for (int i = 0; i < 8; ++i) acc[i] = bf2f(sv[i]) * sl;

    for (int j = beg; j < end; j += 8) {
        int   sK[8];
        float wK[8];
        u16x8 v[8];
#pragma unroll
        for (int k = 0; k < 8; ++k) {
            const int jj = j + k;            // may overrun into pad (safe)
            const int2 e = ew[jj];
            const bool valid = jj < end;     // wave-uniform
            sK[k] = valid ? e.x : 0;
            wK[k] = valid ? __int_as_float(e.y) : 0.0f;
        }
#pragma unroll
        for (int k = 0; k < 8; ++k)
            v[k] = *(const u16x8*)(hW + (size_t)sK[k] * NHID + foff);
#pragma unroll
        for (int k = 0; k < 8; ++k)
#pragma unroll
            for (int i = 0; i < 8; ++i)
                acc[i] += bf2f(v[k][i]) * wK[k];
    }

    const float4 b0v = *(const float4*)(bias + foff);
    const float4 b1v = *(const float4*)(bias + foff + 4);
    u16x8 r;
    r[0] = f2bf(fmaxf(acc[0] + b0v.x, 0.0f));
    r[1] = f2bf(fmaxf(acc[1] + b0v.y, 0.0f));
    r[2] = f2bf(fmaxf(acc[2] + b0v.z, 0.0f));
    r[3] = f2bf(fmaxf(acc[3] + b0v.w, 0.0f));
    r[4] = f2bf(fmaxf(acc[4] + b1v.x, 0.0f));
    r[5] = f2bf(fmaxf(acc[5] + b1v.y, 0.0f));
    r[6] = f2bf(fmaxf(acc[6] + b1v.z, 0.0f));
    r[7] = f2bf(fmaxf(acc[7] + b1v.w, 0.0f));
    *(u16x8*)(out + (size_t)d * NHID + foff) = r;
}

// ================= launch =================
extern "C" void kernel_launch(void* const* d_in, const int* in_sizes, int n_in,
                              void* d_out, int out_size, void* d_ws, size_t ws_size,
                              hipStream_t stream) {
    const float* x       = (const float*)d_in[0];
    const int*   ei      = (const int*)d_in[1];
    const float* W_enc   = (const float*)d_in[2];
    const float* b_enc   = (const float*)d_in[3];
    const float* W_convs = (const float*)d_in[4];
    const float* b_convs = (const float*)d_in[5];
    const float* W_dec   = (const float*)d_in[6];
    const float* b_dec   = (const float*)d_in[7];
    float* out = (float*)d_out;

    const int* src = ei;
    const int* dst = ei + E_EDGES;

    char* ws = (char*)d_ws;
    auto alloc = [&](size_t bytes) {
        char* p = ws;
        ws += (bytes + 255) / 256 * 256;
        return p;
    };
    float* dinv     = (float*)alloc(N_NODES * 4);
    int*   counts   = (int*)  alloc((N_NODES + NBLK) * 4);   // bsums adjacent
    int*   bsums    = counts + N_NODES;
    int*   row_ptr  = (int*)  alloc((N_NODES + 1) * 4);
    int*   cursor   = (int*)  alloc(N_NODES * 4);
    int*   boffs    = (int*)  alloc(NBLK * 4);
    int2*  ew       = (int2*) alloc((E_EDGES + 8) * 8);
    unsigned short* WencT = (unsigned short*)alloc((size_t)NFEAT * NHID * 2);
    unsigned short* WcvT  = (unsigned short*)alloc((size_t)NLAYERS * NHID * NHID * 2);
    unsigned short* WdecT = (unsigned short*)alloc((size_t)NHID * NCLASS * 2);
    unsigned short* B1    = (unsigned short*)alloc((size_t)N_NODES * NHID * 2);
    unsigned short* B2    = (unsigned short*)alloc((size_t)N_NODES * NHID * 2);

    // ---- CSR build + weight conversion (fused) ----
    hipMemsetAsync(counts, 0, (N_NODES + NBLK) * sizeof(int), stream);
    prep_all<<<CNT_BLOCKS + 6 * 256, 256, 0, stream>>>(
        dst, counts, bsums, W_enc, W_convs, W_dec, WencT, WcvT, WdecT);
    scan_bsums<<<1, 64, 0, stream>>>(bsums, boffs);
    write_rowptr<<<NBLK, 256, 0, stream>>>(counts, boffs, row_ptr, cursor, dinv);
    csr_fill<<<(E_EDGES + 255) / 256, 256, 0, stream>>>(src, dst, dinv, cursor, ew);

    const int MBLK64 = (N_NODES + 63) / 64;   // 313

    // ---- encoder (reads fp32 x, converts in staging): 64x128 tile ----
    gemm_mfma<64, 128, 2, 2, true, true, true, true>
        <<<MBLK64 * (NHID / 128), 256, 0, stream>>>(
        x, WencT, b_enc, B1, N_NODES, NHID, NFEAT);

    // ---- conv layers ----
    for (int L = 0; L < NLAYERS; ++L) {
        gemm_mfma<64, 128, 2, 2, false, false, true, false>
            <<<MBLK64 * (NHID / 128), 256, 0, stream>>>(
            B1, WcvT + (size_t)L * NHID * NHID, nullptr, B2, N_NODES, NHID, NHID);
        gcn_aggregate<<<(N_NODES + 3) / 4, 256, 0, stream>>>(
            B2, row_ptr, ew, dinv, b_convs + (size_t)L * NHID, B1);
    }

    // ---- decoder: 64x64 tile ----
    gemm_mfma<64, 64, 2, 2, false, true, false, false>
        <<<MBLK64 * (NCLASS / 64), 256, 0, stream>>>(
        B1, WdecT, b_dec, out, N_NODES, NCLASS, NHID);
}